// Round 10
// baseline (32.007 us; speedup 1.0000x reference)
//
#include <hip/hip_runtime.h>

namespace {

struct c32 { float x, y; };

typedef unsigned int u32x4 __attribute__((ext_vector_type(4)));

__device__ __forceinline__ c32 cmul(c32 a, c32 b) {
    c32 r;
    r.x = fmaf(a.x, b.x, -a.y * b.y);
    r.y = fmaf(a.x, b.y,  a.y * b.x);
    return r;
}

// pack one complex as u32: low u16 = bf16(im), high u16 = bf16(re)  (RTNE)
__device__ __forceinline__ unsigned pack_imre(float im, float re) {
    union { float f; unsigned u; } vi, vr;
    vi.f = im; vr.f = re;
    const unsigned ri = vi.u + 0x7FFF + ((vi.u >> 16) & 1);
    const unsigned rr = vr.u + 0x7FFF + ((vr.u >> 16) & 1);
    return (ri >> 16) | (rr & 0xFFFF0000u);
}

constexpr int NQ   = 10;
constexpr int DIM  = 1024;   // 2^10
constexpr int HDIM = 32;     // 2^5
constexpr int ROWS_PER_BLOCK = 16;   // 64 blocks per batch -> 8 blocks/CU, 32 waves/CU
constexpr int THREADS = 256;

__global__ __launch_bounds__(THREADS)
void r3_kron_kernel(const float* __restrict__ angles, unsigned int* __restrict__ out) {
    __shared__ c32 mats[NQ][2][2];
    __shared__ c32 As[HDIM * HDIM];   // kron of qubits 0..4  (32x32)
    __shared__ c32 Bs[HDIM * HDIM];   // kron of qubits 5..9  (32x32)

    const int tid  = threadIdx.x;
    const int b    = blockIdx.x >> 6;                    // 64 blocks per batch
    const int row0 = (blockIdx.x & 63) * ROWS_PER_BLOCK; // rows row0 .. row0+15
    const int ih   = row0 >> 5;                          // constant over the block
    const int il0  = row0 & 31;

    // --- ten 2x2 matrices from angles ---
    if (tid < NQ) {
        const float* ang = angles + (b * NQ + tid) * 3;
        const float omega = ang[0], theta = ang[1], phi = ang[2];
        float st, ct, s1, c1, s2, c2;
        sincosf(0.5f * theta,           &st, &ct);
        sincosf(0.5f * (phi + omega),   &s1, &c1);
        sincosf(0.5f * (phi - omega),   &s2, &c2);
        // m11 = e^{-i(phi+omega)/2} c ; m12 = -e^{ i(phi-omega)/2} s
        // m21 = e^{-i(phi-omega)/2} s ; m22 =  e^{ i(phi+omega)/2} c
        mats[tid][0][0] = {  ct * c1, -ct * s1 };
        mats[tid][0][1] = { -st * c2, -st * s2 };
        mats[tid][1][0] = {  st * c2, -st * s2 };
        mats[tid][1][1] = {  ct * c1,  ct * s1 };
    }
    __syncthreads();

    // --- build half-krons A (qubits 0..4) and B (qubits 5..9) in LDS ---
    for (int idx = tid; idx < HDIM * HDIM; idx += THREADS) {
        const int r = idx >> 5, c = idx & 31;   // 5-bit row/col
        c32 pa = mats[0][(r >> 4) & 1][(c >> 4) & 1];
        c32 pb = mats[5][(r >> 4) & 1][(c >> 4) & 1];
#pragma unroll
        for (int q = 1; q < 5; ++q) {
            const int s = 4 - q;   // qubit q sits at bit (4-q)
            pa = cmul(pa, mats[q    ][(r >> s) & 1][(c >> s) & 1]);
            pb = cmul(pb, mats[5 + q][(r >> s) & 1][(c >> s) & 1]);
        }
        As[idx] = pa;
        Bs[idx] = pb;
    }
    __syncthreads();

    // --- stream output rows: out[i,j] = A[ih, j>>5] * B[i&31, j&31] ---
    // Verified layout (round-8 probe): row-major (B,D,D), q0 at MSB, each
    // complex element stored as the bf16 pair (IM, RE).
    const c32 a  = As[ih * HDIM + (tid >> 3)];  // jh = t>>3, constant per thread
    const int jl = (4 * tid) & 31;              // low 5 bits of column
    u32x4* outv = reinterpret_cast<u32x4*>(out);

#pragma unroll 4
    for (int r = 0; r < ROWS_PER_BLOCK; ++r) {
        const int il = il0 + r;                 // low 5 bits of global row
        const c32 b0 = Bs[il * HDIM + jl + 0];
        const c32 b1 = Bs[il * HDIM + jl + 1];
        const c32 b2 = Bs[il * HDIM + jl + 2];
        const c32 b3 = Bs[il * HDIM + jl + 3];
        const c32 c0 = cmul(a, b0), c1 = cmul(a, b1);
        const c32 c2 = cmul(a, b2), c3 = cmul(a, b3);
        u32x4 v;
        v[0] = pack_imre(c0.y, c0.x);
        v[1] = pack_imre(c1.y, c1.x);
        v[2] = pack_imre(c2.y, c2.x);
        v[3] = pack_imre(c3.y, c3.x);
        // row base in u32x4 units: (b*1024 + i) * 1024 complex / 4 = (..)*256
        const size_t base = (size_t)(b * DIM + row0 + r) * (DIM / 4);
        __builtin_nontemporal_store(v, outv + base + tid);
    }
}

} // namespace

extern "C" void kernel_launch(void* const* d_in, const int* in_sizes, int n_in,
                              void* d_out, int out_size, void* d_ws, size_t ws_size,
                              hipStream_t stream) {
    const float* angles = (const float*)d_in[0];
    unsigned int* out = (unsigned int*)d_out;
    const int B = in_sizes[0] / (NQ * 3);               // 32
    const dim3 grid(B * (DIM / ROWS_PER_BLOCK));        // 32 * 64 = 2048 blocks
    r3_kron_kernel<<<grid, THREADS, 0, stream>>>(angles, out);
}

// Round 11
// 28.059 us; speedup vs baseline: 1.1407x; 1.1407x over previous
//
#include <hip/hip_runtime.h>

namespace {

struct c32 { float x, y; };

typedef unsigned int u32x4 __attribute__((ext_vector_type(4)));

__device__ __forceinline__ c32 cmul(c32 a, c32 b) {
    c32 r;
    r.x = fmaf(a.x, b.x, -a.y * b.y);
    r.y = fmaf(a.x, b.y,  a.y * b.x);
    return r;
}

// pack one complex as u32: low u16 = bf16(im), high u16 = bf16(re)  (RTNE)
__device__ __forceinline__ unsigned pack_imre(float im, float re) {
    union { float f; unsigned u; } vi, vr;
    vi.f = im; vr.f = re;
    const unsigned ri = vi.u + 0x7FFF + ((vi.u >> 16) & 1);
    const unsigned rr = vr.u + 0x7FFF + ((vr.u >> 16) & 1);
    return (ri >> 16) | (rr & 0xFFFF0000u);
}

constexpr int NQ   = 10;
constexpr int DIM  = 1024;   // 2^10
constexpr int HDIM = 32;     // 2^5
constexpr int ROWS_PER_BLOCK = 32;
constexpr int THREADS = 256;

__global__ __launch_bounds__(THREADS)
void r3_kron_kernel(const float* __restrict__ angles, unsigned int* __restrict__ out) {
    __shared__ c32 mats[NQ][2][2];
    __shared__ c32 Bs[HDIM * HDIM];   // kron of qubits 5..9  (32x32)

    const int tid  = threadIdx.x;
    const int b    = blockIdx.x >> 5;          // 32 blocks per batch
    const int ih   = blockIdx.x & 31;          // rows ih*32 .. ih*32+31

    // --- ten 2x2 matrices from angles ---
    if (tid < NQ) {
        const float* ang = angles + (b * NQ + tid) * 3;
        const float omega = ang[0], theta = ang[1], phi = ang[2];
        float st, ct, s1, c1, s2, c2;
        sincosf(0.5f * theta,           &st, &ct);
        sincosf(0.5f * (phi + omega),   &s1, &c1);
        sincosf(0.5f * (phi - omega),   &s2, &c2);
        // m11 = e^{-i(phi+omega)/2} c ; m12 = -e^{ i(phi-omega)/2} s
        // m21 = e^{-i(phi-omega)/2} s ; m22 =  e^{ i(phi+omega)/2} c
        mats[tid][0][0] = {  ct * c1, -ct * s1 };
        mats[tid][0][1] = { -st * c2, -st * s2 };
        mats[tid][1][0] = {  st * c2, -st * s2 };
        mats[tid][1][1] = {  ct * c1,  ct * s1 };
    }
    __syncthreads();

    // --- build half-kron B (qubits 5..9) in LDS ---
    for (int idx = tid; idx < HDIM * HDIM; idx += THREADS) {
        const int r = idx >> 5, c = idx & 31;   // 5-bit row/col
        c32 pb = mats[5][(r >> 4) & 1][(c >> 4) & 1];
#pragma unroll
        for (int q = 1; q < 5; ++q) {
            const int s = 4 - q;
            pb = cmul(pb, mats[5 + q][(r >> s) & 1][(c >> s) & 1]);
        }
        Bs[idx] = pb;
    }

    // --- this thread's A value: A[ih, tid>>3] from qubits 0..4 directly ---
    {
        // (computed by all threads; mats reads are LDS broadcasts)
    }
    const int jh = tid >> 3;
    c32 a = mats[0][(ih >> 4) & 1][(jh >> 4) & 1];
#pragma unroll
    for (int q = 1; q < 5; ++q) {
        const int s = 4 - q;
        a = cmul(a, mats[q][(ih >> s) & 1][(jh >> s) & 1]);
    }
    __syncthreads();

    // --- stream output rows: out[i,j] = A[ih, j>>5] * B[i&31, j&31] ---
    // Verified layout (round-8 probe): row-major (B,D,D), q0 at MSB, each
    // complex element stored as the bf16 pair (IM, RE). Plain (cached) stores:
    // 128 MiB output fits L3 -> let the cache absorb the stream.
    const int jl = (4 * tid) & 31;              // low 5 bits of column
    u32x4* outv = reinterpret_cast<u32x4*>(out);

#pragma unroll 4
    for (int r = 0; r < ROWS_PER_BLOCK; ++r) {
        const int i = ih * ROWS_PER_BLOCK + r;  // global row; il = r
        const c32 b0 = Bs[r * HDIM + jl + 0];
        const c32 b1 = Bs[r * HDIM + jl + 1];
        const c32 b2 = Bs[r * HDIM + jl + 2];
        const c32 b3 = Bs[r * HDIM + jl + 3];
        const c32 c0 = cmul(a, b0), c1 = cmul(a, b1);
        const c32 c2 = cmul(a, b2), c3 = cmul(a, b3);
        u32x4 v;
        v[0] = pack_imre(c0.y, c0.x);
        v[1] = pack_imre(c1.y, c1.x);
        v[2] = pack_imre(c2.y, c2.x);
        v[3] = pack_imre(c3.y, c3.x);
        outv[(size_t)(b * DIM + i) * (DIM / 4) + tid] = v;
    }
}

} // namespace

extern "C" void kernel_launch(void* const* d_in, const int* in_sizes, int n_in,
                              void* d_out, int out_size, void* d_ws, size_t ws_size,
                              hipStream_t stream) {
    const float* angles = (const float*)d_in[0];
    unsigned int* out = (unsigned int*)d_out;
    const int B = in_sizes[0] / (NQ * 3);               // 32
    const dim3 grid(B * (DIM / ROWS_PER_BLOCK));        // 32 * 32 = 1024 blocks
    r3_kron_kernel<<<grid, THREADS, 0, stream>>>(angles, out);
}

// Round 12
// 27.241 us; speedup vs baseline: 1.1750x; 1.0300x over previous
//
#include <hip/hip_runtime.h>

namespace {

struct c32 { float x, y; };

typedef unsigned int u32x4 __attribute__((ext_vector_type(4)));

__device__ __forceinline__ c32 cmul(c32 a, c32 b) {
    c32 r;
    r.x = fmaf(a.x, b.x, -a.y * b.y);
    r.y = fmaf(a.x, b.y,  a.y * b.x);
    return r;
}

// one complex -> u32 (lo = bf16(im), hi = bf16(re)) via HW packed cvt (RTNE)
__device__ __forceinline__ unsigned pack_imre(float im, float re) {
    unsigned r;
    asm("v_cvt_pk_bf16_f32 %0, %1, %2" : "=v"(r) : "v"(im), "v"(re));
    return r;
}

constexpr int NQ   = 10;
constexpr int DIM  = 1024;   // 2^10
constexpr int HDIM = 32;     // 2^5
constexpr int ROWS_PER_BLOCK = 32;
constexpr int THREADS = 256;

__global__ __launch_bounds__(THREADS)
void r3_kron_kernel(const float* __restrict__ angles, unsigned int* __restrict__ out) {
    __shared__ c32 mats[NQ][2][2];
    __shared__ c32 Bs[HDIM * HDIM];   // kron of qubits 5..9  (32x32)

    const int tid  = threadIdx.x;
    const int b    = blockIdx.x >> 5;          // 32 blocks per batch
    const int ih   = blockIdx.x & 31;          // rows ih*32 .. ih*32+31

    // --- ten 2x2 matrices from angles ---
    if (tid < NQ) {
        const float* ang = angles + (b * NQ + tid) * 3;
        const float omega = ang[0], theta = ang[1], phi = ang[2];
        float st, ct, s1, c1, s2, c2;
        sincosf(0.5f * theta,           &st, &ct);
        sincosf(0.5f * (phi + omega),   &s1, &c1);
        sincosf(0.5f * (phi - omega),   &s2, &c2);
        // m11 = e^{-i(phi+omega)/2} c ; m12 = -e^{ i(phi-omega)/2} s
        // m21 = e^{-i(phi-omega)/2} s ; m22 =  e^{ i(phi+omega)/2} c
        mats[tid][0][0] = {  ct * c1, -ct * s1 };
        mats[tid][0][1] = { -st * c2, -st * s2 };
        mats[tid][1][0] = {  st * c2, -st * s2 };
        mats[tid][1][1] = {  ct * c1,  ct * s1 };
    }
    __syncthreads();

    // --- build half-kron B (qubits 5..9) in LDS ---
    for (int idx = tid; idx < HDIM * HDIM; idx += THREADS) {
        const int r = idx >> 5, c = idx & 31;   // 5-bit row/col
        c32 pb = mats[5][(r >> 4) & 1][(c >> 4) & 1];
#pragma unroll
        for (int q = 1; q < 5; ++q) {
            const int s = 4 - q;
            pb = cmul(pb, mats[5 + q][(r >> s) & 1][(c >> s) & 1]);
        }
        Bs[idx] = pb;
    }

    // --- this thread's A value: A[ih, tid>>3] from qubits 0..4 directly ---
    const int jh = tid >> 3;
    c32 a = mats[0][(ih >> 4) & 1][(jh >> 4) & 1];
#pragma unroll
    for (int q = 1; q < 5; ++q) {
        const int s = 4 - q;
        a = cmul(a, mats[q][(ih >> s) & 1][(jh >> s) & 1]);
    }
    __syncthreads();

    // --- stream output rows: out[i,j] = A[ih, j>>5] * B[i&31, j&31] ---
    // Verified layout (round-8 probe): row-major (B,D,D), q0 at MSB, each
    // complex element stored as the bf16 pair (IM, RE). Plain (cached) stores:
    // L2/L3 absorbs the burst (round-11: +10% vs nontemporal).
    const int jl = (4 * tid) & 31;              // low 5 bits of column
    u32x4* outv = reinterpret_cast<u32x4*>(out);

#pragma unroll 4
    for (int r = 0; r < ROWS_PER_BLOCK; ++r) {
        const int i = ih * ROWS_PER_BLOCK + r;  // global row; il = r
        const c32 b0 = Bs[r * HDIM + jl + 0];
        const c32 b1 = Bs[r * HDIM + jl + 1];
        const c32 b2 = Bs[r * HDIM + jl + 2];
        const c32 b3 = Bs[r * HDIM + jl + 3];
        const c32 c0 = cmul(a, b0), c1 = cmul(a, b1);
        const c32 c2 = cmul(a, b2), c3 = cmul(a, b3);
        u32x4 v;
        v[0] = pack_imre(c0.y, c0.x);
        v[1] = pack_imre(c1.y, c1.x);
        v[2] = pack_imre(c2.y, c2.x);
        v[3] = pack_imre(c3.y, c3.x);
        outv[(size_t)(b * DIM + i) * (DIM / 4) + tid] = v;
    }
}

} // namespace

extern "C" void kernel_launch(void* const* d_in, const int* in_sizes, int n_in,
                              void* d_out, int out_size, void* d_ws, size_t ws_size,
                              hipStream_t stream) {
    const float* angles = (const float*)d_in[0];
    unsigned int* out = (unsigned int*)d_out;
    const int B = in_sizes[0] / (NQ * 3);               // 32
    const dim3 grid(B * (DIM / ROWS_PER_BLOCK));        // 32 * 32 = 1024 blocks
    r3_kron_kernel<<<grid, THREADS, 0, stream>>>(angles, out);
}